// Round 1
// baseline (256.125 us; speedup 1.0000x reference)
//
#include <hip/hip_runtime.h>

#define N_NODES 50000
#define N_EDGES 800000
#define D 64

// ---------------- deg init: self-loop weight 1.0 ----------------
__global__ __launch_bounds__(256) void k_deg_init(float* __restrict__ deg) {
    int i = blockIdx.x * blockDim.x + threadIdx.x;
    if (i < N_NODES) deg[i] = 1.0f;
}

// ---------------- deg scatter: deg[col[e]] += ew[e] ----------------
__global__ __launch_bounds__(256) void k_deg_scatter(const int* __restrict__ col,
                                                     const float* __restrict__ ew,
                                                     float* __restrict__ deg) {
    int e = blockIdx.x * blockDim.x + threadIdx.x;
    if (e < N_EDGES) atomicAdd(&deg[col[e]], ew[e]);
}

// ---------------- deg -> deg^-1/2 in place ----------------
__global__ __launch_bounds__(256) void k_rsqrt(float* __restrict__ deg) {
    int i = blockIdx.x * blockDim.x + threadIdx.x;
    if (i < N_NODES) {
        float d = deg[i];
        deg[i] = (d > 0.0f) ? rsqrtf(d) : 0.0f;
    }
}

// ---------------- xw = x @ W; out = xw * dis^2 + bias (self-loop fused) ----------------
__global__ __launch_bounds__(256) void k_xw_init(const float* __restrict__ x,
                                                 const float* __restrict__ W,
                                                 const float* __restrict__ bias,
                                                 const float* __restrict__ dis,
                                                 float* __restrict__ xw,
                                                 float* __restrict__ out) {
    __shared__ float Ws[D * D];     // 16 KiB
    __shared__ float xs[4][D];      // one row per wave
    int tid = threadIdx.x;
    for (int i = tid; i < D * D; i += 256) Ws[i] = W[i];
    __syncthreads();

    int wave = tid >> 6;
    int lane = tid & 63;
    float b = bias[lane];

    for (int base = blockIdx.x * 4; base < N_NODES; base += gridDim.x * 4) {
        int r = base + wave;
        if (r < N_NODES) {
            // stage row r of x; wave-private LDS slab, wave-synchronous (no barrier needed)
            xs[wave][lane] = x[r * D + lane];
            float acc = 0.0f;
#pragma unroll
            for (int k = 0; k < D; ++k) {
                // xs[wave][k]: same-address broadcast (free); Ws[k*64+lane]: 2-way alias (free)
                acc = fmaf(xs[wave][k], Ws[k * D + lane], acc);
            }
            xw[r * D + lane] = acc;
            float di = dis[r];
            out[r * D + lane] = acc * (di * di) + b;
        }
    }
}

// ---------------- edge messages: out[col] += xw[row] * (dis[row]*ew*dis[col]) ----------------
__global__ __launch_bounds__(256) void k_edge(const int* __restrict__ ei,
                                              const float* __restrict__ ew,
                                              const float* __restrict__ dis,
                                              const float* __restrict__ xw,
                                              float* __restrict__ out) {
    int t = blockIdx.x * blockDim.x + threadIdx.x;  // up to 51.2M < 2^31
    int e = t >> 6;
    int c = t & 63;
    if (e < N_EDGES) {
        int row = ei[e];             // source (gather)
        int col = ei[N_EDGES + e];   // target (scatter)
        float nrm = dis[row] * ew[e] * dis[col];
        float v = xw[row * D + c] * nrm;
        atomicAdd(&out[col * D + c], v);
    }
}

extern "C" void kernel_launch(void* const* d_in, const int* in_sizes, int n_in,
                              void* d_out, int out_size, void* d_ws, size_t ws_size,
                              hipStream_t stream) {
    const float* x    = (const float*)d_in[0];
    const float* W    = (const float*)d_in[1];
    const float* bias = (const float*)d_in[2];
    const float* ew   = (const float*)d_in[3];
    const int*   ei   = (const int*)d_in[4];   // (2, E) flat: [0:E) = row/src, [E:2E) = col/dst
    float* out = (float*)d_out;

    float* xw  = (float*)d_ws;                 // N*D floats = 12.8 MB
    float* deg = xw + (size_t)N_NODES * D;     // N floats; becomes dis in place

    k_deg_init<<<(N_NODES + 255) / 256, 256, 0, stream>>>(deg);
    k_deg_scatter<<<(N_EDGES + 255) / 256, 256, 0, stream>>>(ei + N_EDGES, ew, deg);
    k_rsqrt<<<(N_NODES + 255) / 256, 256, 0, stream>>>(deg);
    k_xw_init<<<2048, 256, 0, stream>>>(x, W, bias, deg, xw, out);

    int edge_threads_blocks = (N_EDGES * 64) / 256;  // 200000 blocks, exact multiple
    k_edge<<<edge_threads_blocks, 256, 0, stream>>>(ei, ew, deg, xw, out);
}

// Round 2
// 205.591 us; speedup vs baseline: 1.2458x; 1.2458x over previous
//
#include <hip/hip_runtime.h>

#define N_NODES 50000
#define N_EDGES 800000
#define D 64

// ---------- init: deg = 1.0 (self-loop weight), cnt = 0 ----------
__global__ __launch_bounds__(256) void k_init(float* __restrict__ deg, int* __restrict__ cnt) {
    int i = blockIdx.x * blockDim.x + threadIdx.x;
    if (i < N_NODES) { deg[i] = 1.0f; cnt[i] = 0; }
}

// ---------- deg[col] += ew; cnt[col] += 1 ----------
__global__ __launch_bounds__(256) void k_deg_cnt(const int* __restrict__ col,
                                                 const float* __restrict__ ew,
                                                 float* __restrict__ deg,
                                                 int* __restrict__ cnt) {
    int e = blockIdx.x * blockDim.x + threadIdx.x;
    if (e < N_EDGES) {
        int c = col[e];
        atomicAdd(&deg[c], ew[e]);
        atomicAdd(&cnt[c], 1);
    }
}

// ---------- deg -> deg^-1/2 in place ----------
__global__ __launch_bounds__(256) void k_rsqrt(float* __restrict__ deg) {
    int i = blockIdx.x * blockDim.x + threadIdx.x;
    if (i < N_NODES) {
        float d = deg[i];
        deg[i] = (d > 0.0f) ? rsqrtf(d) : 0.0f;
    }
}

// ---------- scan pass 1: per-block (512 elems) exclusive scan + block totals ----------
__global__ __launch_bounds__(256) void k_scan1(const int* __restrict__ cnt,
                                               int* __restrict__ start,
                                               int* __restrict__ partials) {
    __shared__ int s[512];
    int t = threadIdx.x, b = blockIdx.x;
    int i0 = b * 512 + t, i1 = i0 + 256;
    int v0 = (i0 < N_NODES) ? cnt[i0] : 0;
    int v1 = (i1 < N_NODES) ? cnt[i1] : 0;
    s[t] = v0; s[t + 256] = v1;
    __syncthreads();
    for (int off = 1; off < 512; off <<= 1) {
        int a0 = (t >= off) ? s[t - off] : 0;
        int a1 = s[t + 256 - off];   // t+256-off >= 0 always (off <= 256)
        __syncthreads();
        s[t] += a0; s[t + 256] += a1;
        __syncthreads();
    }
    if (i0 < N_NODES) start[i0] = s[t] - v0;
    if (i1 < N_NODES) start[i1] = s[t + 256] - v1;
    if (t == 255) partials[b] = s[511];
}

// ---------- scan pass 2: exclusive scan of 98 block totals ----------
__global__ __launch_bounds__(128) void k_scan2(int* __restrict__ partials, int nblk) {
    __shared__ int s[128];
    int t = threadIdx.x;
    int v = (t < nblk) ? partials[t] : 0;
    s[t] = v;
    __syncthreads();
    for (int off = 1; off < 128; off <<= 1) {
        int a = (t >= off) ? s[t - off] : 0;
        __syncthreads();
        s[t] += a;
        __syncthreads();
    }
    if (t < nblk) partials[t] = s[t] - v;
}

// ---------- scan pass 3: add block offsets; copy to cursor; set start[N] ----------
__global__ __launch_bounds__(256) void k_scan3(int* __restrict__ start,
                                               const int* __restrict__ partials,
                                               int* __restrict__ cursor) {
    int t = threadIdx.x, b = blockIdx.x;
    int add = partials[b];
    int i0 = b * 512 + t, i1 = i0 + 256;
    if (i0 < N_NODES) { int v = start[i0] + add; start[i0] = v; cursor[i0] = v; }
    if (i1 < N_NODES) { int v = start[i1] + add; start[i1] = v; cursor[i1] = v; }
    if (b == 0 && t == 0) start[N_NODES] = N_EDGES;
}

// ---------- xw = x @ W  (8 rows x 4 cols per thread, float4 LDS reads) ----------
__global__ __launch_bounds__(256) void k_xw(const float* __restrict__ x,
                                            const float* __restrict__ W,
                                            float* __restrict__ xw) {
    __shared__ float Ws[64 * 64];     // 16 KiB, row-major [k][c]
    __shared__ float xs[128 * 68];    // 34 KiB, pad 68 -> in-wave rows on distinct banks
    int t = threadIdx.x;
    int r0 = blockIdx.x * 128;

    for (int i = t; i < 1024; i += 256)
        ((float4*)Ws)[i] = ((const float4*)W)[i];
    for (int i = t; i < 2048; i += 256) {
        int row = i >> 4, k4 = i & 15;
        int gr = r0 + row;
        float4 v = make_float4(0.f, 0.f, 0.f, 0.f);
        if (gr < N_NODES) v = ((const float4*)x)[gr * 16 + k4];
        *(float4*)&xs[row * 68 + k4 * 4] = v;
    }
    __syncthreads();

    int cg = t & 15;        // 4-col group
    int rg = t >> 4;        // 0..15; rows rg + 16*i
    float4 acc[8];
#pragma unroll
    for (int i = 0; i < 8; ++i) acc[i] = make_float4(0.f, 0.f, 0.f, 0.f);

    for (int k4 = 0; k4 < 16; ++k4) {
        float4 xv[8];
#pragma unroll
        for (int i = 0; i < 8; ++i)
            xv[i] = *(const float4*)&xs[(rg + 16 * i) * 68 + k4 * 4];
        float4 w0 = *(const float4*)&Ws[(k4 * 4 + 0) * 64 + cg * 4];
        float4 w1 = *(const float4*)&Ws[(k4 * 4 + 1) * 64 + cg * 4];
        float4 w2 = *(const float4*)&Ws[(k4 * 4 + 2) * 64 + cg * 4];
        float4 w3 = *(const float4*)&Ws[(k4 * 4 + 3) * 64 + cg * 4];
#pragma unroll
        for (int i = 0; i < 8; ++i) {
            acc[i].x = fmaf(xv[i].x, w0.x, acc[i].x); acc[i].y = fmaf(xv[i].x, w0.y, acc[i].y);
            acc[i].z = fmaf(xv[i].x, w0.z, acc[i].z); acc[i].w = fmaf(xv[i].x, w0.w, acc[i].w);
            acc[i].x = fmaf(xv[i].y, w1.x, acc[i].x); acc[i].y = fmaf(xv[i].y, w1.y, acc[i].y);
            acc[i].z = fmaf(xv[i].y, w1.z, acc[i].z); acc[i].w = fmaf(xv[i].y, w1.w, acc[i].w);
            acc[i].x = fmaf(xv[i].z, w2.x, acc[i].x); acc[i].y = fmaf(xv[i].z, w2.y, acc[i].y);
            acc[i].z = fmaf(xv[i].z, w2.z, acc[i].z); acc[i].w = fmaf(xv[i].z, w2.w, acc[i].w);
            acc[i].x = fmaf(xv[i].w, w3.x, acc[i].x); acc[i].y = fmaf(xv[i].w, w3.y, acc[i].y);
            acc[i].z = fmaf(xv[i].w, w3.z, acc[i].z); acc[i].w = fmaf(xv[i].w, w3.w, acc[i].w);
        }
    }

#pragma unroll
    for (int i = 0; i < 8; ++i) {
        int row = r0 + rg + 16 * i;
        if (row < N_NODES) ((float4*)xw)[row * 16 + cg] = acc[i];
    }
}

// ---------- bucket-scatter edge records (src, norm) by target ----------
__global__ __launch_bounds__(256) void k_scatter(const int* __restrict__ ei,
                                                 const float* __restrict__ ew,
                                                 const float* __restrict__ dis,
                                                 int* __restrict__ cursor,
                                                 int2* __restrict__ rec) {
    int e = blockIdx.x * blockDim.x + threadIdx.x;
    if (e < N_EDGES) {
        int row = ei[e];
        int col = ei[N_EDGES + e];
        float w = dis[row] * ew[e] * dis[col];
        int pos = atomicAdd(&cursor[col], 1);
        rec[pos] = make_int2(row, __float_as_int(w));
    }
}

// ---------- per-node gather: one wave per node, lane = channel ----------
__global__ __launch_bounds__(256) void k_gather(const int* __restrict__ start,
                                                const int2* __restrict__ rec,
                                                const float* __restrict__ xw,
                                                const float* __restrict__ dis,
                                                const float* __restrict__ bias,
                                                float* __restrict__ out) {
    int wave = threadIdx.x >> 6;
    int c = threadIdx.x & 63;
    int n = blockIdx.x * 4 + wave;   // 12500 * 4 = 50000 exact
    float di = dis[n];
    float acc = fmaf(xw[n * D + c], di * di, bias[c]);   // self-loop + bias
    int j = start[n], jend = start[n + 1];
    int2 r = (j < jend) ? rec[j] : make_int2(0, 0);
    while (j < jend) {
        int2 cur = r;
        if (j + 1 < jend) r = rec[j + 1];          // prefetch next record
        acc = fmaf(xw[cur.x * D + c], __int_as_float(cur.y), acc);
        ++j;
    }
    out[n * D + c] = acc;
}

extern "C" void kernel_launch(void* const* d_in, const int* in_sizes, int n_in,
                              void* d_out, int out_size, void* d_ws, size_t ws_size,
                              hipStream_t stream) {
    const float* x    = (const float*)d_in[0];
    const float* W    = (const float*)d_in[1];
    const float* bias = (const float*)d_in[2];
    const float* ew   = (const float*)d_in[3];
    const int*   ei   = (const int*)d_in[4];   // (2,E) flat: [0:E) src, [E:2E) dst
    float* out = (float*)d_out;

    // workspace layout (4B units); rec first for 8B alignment
    int2*  rec     = (int2*)d_ws;                              // 800000 * 8B = 6.4 MB
    float* xw      = (float*)d_ws + 2 * (size_t)N_EDGES;       // 12.8 MB
    float* deg     = xw + (size_t)N_NODES * D;                 // 200 KB (becomes dis)
    int*   cnt     = (int*)(deg + N_NODES);                    // 200 KB
    int*   start   = cnt + N_NODES;                            // 200 KB (+1)
    int*   cursor  = start + N_NODES + 1;                      // 200 KB
    int*   partials = cursor + N_NODES;                        // 98 ints

    const int NB_SCAN = (N_NODES + 511) / 512;   // 98

    k_init<<<(N_NODES + 255) / 256, 256, 0, stream>>>(deg, cnt);
    k_deg_cnt<<<N_EDGES / 256, 256, 0, stream>>>(ei + N_EDGES, ew, deg, cnt);
    k_rsqrt<<<(N_NODES + 255) / 256, 256, 0, stream>>>(deg);
    k_scan1<<<NB_SCAN, 256, 0, stream>>>(cnt, start, partials);
    k_scan2<<<1, 128, 0, stream>>>(partials, NB_SCAN);
    k_scan3<<<NB_SCAN, 256, 0, stream>>>(start, partials, cursor);
    k_xw<<<(N_NODES + 127) / 128, 256, 0, stream>>>(x, W, xw);
    k_scatter<<<N_EDGES / 256, 256, 0, stream>>>(ei, ew, deg, cursor, rec);
    k_gather<<<N_NODES / 4, 256, 0, stream>>>(start, rec, xw, deg, bias, out);
}

// Round 3
// 203.207 us; speedup vs baseline: 1.2604x; 1.0117x over previous
//
#include <hip/hip_runtime.h>

#define N_NODES 50000
#define N_EDGES 800000
#define D 64
#define R 8   // histogram/cursor replication factor

// ---------- zero deg_r (float) and cnt_r (int): 2*R*N words ----------
__global__ __launch_bounds__(256) void k_zero(float* __restrict__ deg_r, int* __restrict__ cnt_r) {
    int i = blockIdx.x * blockDim.x + threadIdx.x;   // 800000 threads exact
    deg_r[i] = 0.0f;
    cnt_r[i] = 0;
}

// ---------- replicated histogram: deg_r[r][col] += ew; cnt_r[r][col]++ ----------
__global__ __launch_bounds__(256) void k_hist(const int* __restrict__ col,
                                              const float* __restrict__ ew,
                                              float* __restrict__ deg_r,
                                              int* __restrict__ cnt_r) {
    int e = blockIdx.x * blockDim.x + threadIdx.x;
    if (e < N_EDGES) {
        int c = col[e];
        int r = e & (R - 1);
        atomicAdd(&deg_r[r * N_NODES + c], ew[e]);
        atomicAdd(&cnt_r[r * N_NODES + c], 1);
    }
}

// ---------- reduce replicas: dis = rsqrt(1 + sum deg_r), cnttot = sum cnt_r ----------
__global__ __launch_bounds__(256) void k_dis(const float* __restrict__ deg_r,
                                             const int* __restrict__ cnt_r,
                                             float* __restrict__ dis,
                                             int* __restrict__ cnttot) {
    int n = blockIdx.x * blockDim.x + threadIdx.x;
    if (n < N_NODES) {
        float d = 1.0f;   // self-loop weight
        int ct = 0;
#pragma unroll
        for (int r = 0; r < R; ++r) {
            d += deg_r[r * N_NODES + n];
            ct += cnt_r[r * N_NODES + n];
        }
        dis[n] = (d > 0.0f) ? rsqrtf(d) : 0.0f;
        cnttot[n] = ct;
    }
}

// ---------- scan pass 1: per-block (512 elems) exclusive scan + block totals ----------
__global__ __launch_bounds__(256) void k_scan1(const int* __restrict__ cnt,
                                               int* __restrict__ start,
                                               int* __restrict__ partials) {
    __shared__ int s[512];
    int t = threadIdx.x, b = blockIdx.x;
    int i0 = b * 512 + t, i1 = i0 + 256;
    int v0 = (i0 < N_NODES) ? cnt[i0] : 0;
    int v1 = (i1 < N_NODES) ? cnt[i1] : 0;
    s[t] = v0; s[t + 256] = v1;
    __syncthreads();
    for (int off = 1; off < 512; off <<= 1) {
        int a0 = (t >= off) ? s[t - off] : 0;
        int a1 = s[t + 256 - off];
        __syncthreads();
        s[t] += a0; s[t + 256] += a1;
        __syncthreads();
    }
    if (i0 < N_NODES) start[i0] = s[t] - v0;
    if (i1 < N_NODES) start[i1] = s[t + 256] - v1;
    if (t == 255) partials[b] = s[511];
}

// ---------- scan pass 2: exclusive scan of block totals ----------
__global__ __launch_bounds__(128) void k_scan2(int* __restrict__ partials, int nblk) {
    __shared__ int s[128];
    int t = threadIdx.x;
    int v = (t < nblk) ? partials[t] : 0;
    s[t] = v;
    __syncthreads();
    for (int off = 1; off < 128; off <<= 1) {
        int a = (t >= off) ? s[t - off] : 0;
        __syncthreads();
        s[t] += a;
        __syncthreads();
    }
    if (t < nblk) partials[t] = s[t] - v;
}

// ---------- scan pass 3: finalize start; derive per-replica cursors ----------
__global__ __launch_bounds__(256) void k_scan3(int* __restrict__ start,
                                               const int* __restrict__ partials,
                                               const int* __restrict__ cnt_r,
                                               int* __restrict__ cur_r) {
    int t = threadIdx.x, b = blockIdx.x;
    int add = partials[b];
    int idx[2] = { b * 512 + t, b * 512 + t + 256 };
#pragma unroll
    for (int q = 0; q < 2; ++q) {
        int i = idx[q];
        if (i < N_NODES) {
            int s0 = start[i] + add;
            start[i] = s0;
            int acc = s0;
#pragma unroll
            for (int r = 0; r < R; ++r) {
                cur_r[r * N_NODES + i] = acc;
                acc += cnt_r[r * N_NODES + i];
            }
        }
    }
    if (b == 0 && t == 0) start[N_NODES] = N_EDGES;
}

// ---------- xw = x @ W  (8 rows x 4 cols per thread, float4 LDS reads) ----------
__global__ __launch_bounds__(256) void k_xw(const float* __restrict__ x,
                                            const float* __restrict__ W,
                                            float* __restrict__ xw) {
    __shared__ float Ws[64 * 64];
    __shared__ float xs[128 * 68];
    int t = threadIdx.x;
    int r0 = blockIdx.x * 128;

    for (int i = t; i < 1024; i += 256)
        ((float4*)Ws)[i] = ((const float4*)W)[i];
    for (int i = t; i < 2048; i += 256) {
        int row = i >> 4, k4 = i & 15;
        int gr = r0 + row;
        float4 v = make_float4(0.f, 0.f, 0.f, 0.f);
        if (gr < N_NODES) v = ((const float4*)x)[gr * 16 + k4];
        *(float4*)&xs[row * 68 + k4 * 4] = v;
    }
    __syncthreads();

    int cg = t & 15;
    int rg = t >> 4;
    float4 acc[8];
#pragma unroll
    for (int i = 0; i < 8; ++i) acc[i] = make_float4(0.f, 0.f, 0.f, 0.f);

    for (int k4 = 0; k4 < 16; ++k4) {
        float4 xv[8];
#pragma unroll
        for (int i = 0; i < 8; ++i)
            xv[i] = *(const float4*)&xs[(rg + 16 * i) * 68 + k4 * 4];
        float4 w0 = *(const float4*)&Ws[(k4 * 4 + 0) * 64 + cg * 4];
        float4 w1 = *(const float4*)&Ws[(k4 * 4 + 1) * 64 + cg * 4];
        float4 w2 = *(const float4*)&Ws[(k4 * 4 + 2) * 64 + cg * 4];
        float4 w3 = *(const float4*)&Ws[(k4 * 4 + 3) * 64 + cg * 4];
#pragma unroll
        for (int i = 0; i < 8; ++i) {
            acc[i].x = fmaf(xv[i].x, w0.x, acc[i].x); acc[i].y = fmaf(xv[i].x, w0.y, acc[i].y);
            acc[i].z = fmaf(xv[i].x, w0.z, acc[i].z); acc[i].w = fmaf(xv[i].x, w0.w, acc[i].w);
            acc[i].x = fmaf(xv[i].y, w1.x, acc[i].x); acc[i].y = fmaf(xv[i].y, w1.y, acc[i].y);
            acc[i].z = fmaf(xv[i].y, w1.z, acc[i].z); acc[i].w = fmaf(xv[i].y, w1.w, acc[i].w);
            acc[i].x = fmaf(xv[i].z, w2.x, acc[i].x); acc[i].y = fmaf(xv[i].z, w2.y, acc[i].y);
            acc[i].z = fmaf(xv[i].z, w2.z, acc[i].z); acc[i].w = fmaf(xv[i].z, w2.w, acc[i].w);
            acc[i].x = fmaf(xv[i].w, w3.x, acc[i].x); acc[i].y = fmaf(xv[i].w, w3.y, acc[i].y);
            acc[i].z = fmaf(xv[i].w, w3.z, acc[i].z); acc[i].w = fmaf(xv[i].w, w3.w, acc[i].w);
        }
    }

#pragma unroll
    for (int i = 0; i < 8; ++i) {
        int row = r0 + rg + 16 * i;
        if (row < N_NODES) ((float4*)xw)[row * 16 + cg] = acc[i];
    }
}

// ---------- bucket-scatter edge records (src, norm); per-replica cursors ----------
__global__ __launch_bounds__(256) void k_scatter(const int* __restrict__ ei,
                                                 const float* __restrict__ ew,
                                                 const float* __restrict__ dis,
                                                 int* __restrict__ cur_r,
                                                 int2* __restrict__ rec) {
    int e = blockIdx.x * blockDim.x + threadIdx.x;
    if (e < N_EDGES) {
        int row = ei[e];
        int col = ei[N_EDGES + e];
        int r = e & (R - 1);
        float w = dis[row] * ew[e] * dis[col];
        int pos = atomicAdd(&cur_r[r * N_NODES + col], 1);
        rec[pos] = make_int2(row, __float_as_int(w));
    }
}

// ---------- per-node gather: one wave per node, lane = channel ----------
__global__ __launch_bounds__(256) void k_gather(const int* __restrict__ start,
                                                const int2* __restrict__ rec,
                                                const float* __restrict__ xw,
                                                const float* __restrict__ dis,
                                                const float* __restrict__ bias,
                                                float* __restrict__ out) {
    int wave = threadIdx.x >> 6;
    int c = threadIdx.x & 63;
    int n = blockIdx.x * 4 + wave;   // 12500 * 4 = 50000 exact
    float di = dis[n];
    float acc = fmaf(xw[n * D + c], di * di, bias[c]);   // self-loop + bias
    int j = start[n], jend = start[n + 1];
    int2 r = (j < jend) ? rec[j] : make_int2(0, 0);
    while (j < jend) {
        int2 cur = r;
        if (j + 1 < jend) r = rec[j + 1];
        acc = fmaf(xw[cur.x * D + c], __int_as_float(cur.y), acc);
        ++j;
    }
    out[n * D + c] = acc;
}

extern "C" void kernel_launch(void* const* d_in, const int* in_sizes, int n_in,
                              void* d_out, int out_size, void* d_ws, size_t ws_size,
                              hipStream_t stream) {
    const float* x    = (const float*)d_in[0];
    const float* W    = (const float*)d_in[1];
    const float* bias = (const float*)d_in[2];
    const float* ew   = (const float*)d_in[3];
    const int*   ei   = (const int*)d_in[4];   // (2,E) flat: [0:E) src, [E:2E) dst
    float* out = (float*)d_out;

    // workspace layout (4B units); rec first for 8B alignment
    int2*  rec      = (int2*)d_ws;                              // 6.4 MB
    float* xw       = (float*)d_ws + 2 * (size_t)N_EDGES;       // 12.8 MB
    float* deg_r    = xw + (size_t)N_NODES * D;                 // R*N = 1.6 MB
    int*   cnt_r    = (int*)(deg_r + R * N_NODES);              // 1.6 MB
    int*   cur_r    = cnt_r + R * N_NODES;                      // 1.6 MB
    float* dis      = (float*)(cur_r + R * N_NODES);            // 200 KB
    int*   cnttot   = (int*)(dis + N_NODES);                    // 200 KB
    int*   start    = cnttot + N_NODES;                         // 200 KB (+1)
    int*   partials = start + N_NODES + 1;                      // 98 ints

    const int NB_SCAN = (N_NODES + 511) / 512;   // 98

    k_zero<<<(2 * R * N_NODES) / 256 + 1, 256, 0, stream>>>(deg_r, cnt_r);
    k_hist<<<N_EDGES / 256, 256, 0, stream>>>(ei + N_EDGES, ew, deg_r, cnt_r);
    k_dis<<<(N_NODES + 255) / 256, 256, 0, stream>>>(deg_r, cnt_r, dis, cnttot);
    k_scan1<<<NB_SCAN, 256, 0, stream>>>(cnttot, start, partials);
    k_scan2<<<1, 128, 0, stream>>>(partials, NB_SCAN);
    k_scan3<<<NB_SCAN, 256, 0, stream>>>(start, partials, cnt_r, cur_r);
    k_xw<<<(N_NODES + 127) / 128, 256, 0, stream>>>(x, W, xw);
    k_scatter<<<N_EDGES / 256, 256, 0, stream>>>(ei, ew, dis, cur_r, rec);
    k_gather<<<N_NODES / 4, 256, 0, stream>>>(start, rec, xw, dis, bias, out);
}

// Round 4
// 138.721 us; speedup vs baseline: 1.8463x; 1.4649x over previous
//
#include <hip/hip_runtime.h>

#define N_NODES 50000
#define N_EDGES 800000
#define D 64
#define NCHUNK 64
#define CHUNK_E (N_EDGES / NCHUNK)   // 12500 edges per chunk
#define NRANGE 8
#define RANGE_N 8192                 // nodes per range (pow2); 8*8192 >= 50000

// ---------- LDS histogram + local ranks (no global atomics) ----------
// grid = NCHUNK * NRANGE blocks; block (i,j) histograms chunk i's edges whose
// target falls in range j. LDS atomicAdd's return value = rank within (chunk,node).
__global__ __launch_bounds__(256) void k_hist(const int* __restrict__ col,
                                              unsigned short* __restrict__ part,
                                              unsigned short* __restrict__ lrank) {
    __shared__ unsigned int h[RANGE_N];   // 32 KiB
    int i = blockIdx.x >> 3;   // chunk 0..63
    int j = blockIdx.x & 7;    // range 0..7
    int t = threadIdx.x;
    for (int k = t; k < RANGE_N; k += 256) h[k] = 0;
    __syncthreads();
    int base = i * CHUNK_E;
    for (int e = base + t; e < base + CHUNK_E; e += 256) {
        int c = col[e];
        if ((c >> 13) == j) {
            unsigned int lr = atomicAdd(&h[c & (RANGE_N - 1)], 1u);
            lrank[e] = (unsigned short)lr;
        }
    }
    __syncthreads();
    for (int k = t; k < RANGE_N; k += 256) {
        int n = j * RANGE_N + k;
        if (n < N_NODES) part[(size_t)i * N_NODES + n] = (unsigned short)h[k];
    }
}

// ---------- per-node exclusive scan over the 64 chunk counts ----------
__global__ __launch_bounds__(256) void k_scanchunks(unsigned short* __restrict__ part,
                                                    int* __restrict__ cnttot) {
    int n = blockIdx.x * blockDim.x + threadIdx.x;
    if (n < N_NODES) {
        unsigned int run = 0;
#pragma unroll 8
        for (int i = 0; i < NCHUNK; ++i) {
            size_t idx = (size_t)i * N_NODES + n;
            unsigned int v = part[idx];
            part[idx] = (unsigned short)run;
            run += v;
        }
        cnttot[n] = (int)run;
    }
}

// ---------- scan pass 1: per-block (512 elems) exclusive scan + block totals ----------
__global__ __launch_bounds__(256) void k_scan1(const int* __restrict__ cnt,
                                               int* __restrict__ start,
                                               int* __restrict__ partials) {
    __shared__ int s[512];
    int t = threadIdx.x, b = blockIdx.x;
    int i0 = b * 512 + t, i1 = i0 + 256;
    int v0 = (i0 < N_NODES) ? cnt[i0] : 0;
    int v1 = (i1 < N_NODES) ? cnt[i1] : 0;
    s[t] = v0; s[t + 256] = v1;
    __syncthreads();
    for (int off = 1; off < 512; off <<= 1) {
        int a0 = (t >= off) ? s[t - off] : 0;
        int a1 = s[t + 256 - off];
        __syncthreads();
        s[t] += a0; s[t + 256] += a1;
        __syncthreads();
    }
    if (i0 < N_NODES) start[i0] = s[t] - v0;
    if (i1 < N_NODES) start[i1] = s[t + 256] - v1;
    if (t == 255) partials[b] = s[511];
}

// ---------- scan pass 2: exclusive scan of block totals ----------
__global__ __launch_bounds__(128) void k_scan2(int* __restrict__ partials, int nblk) {
    __shared__ int s[128];
    int t = threadIdx.x;
    int v = (t < nblk) ? partials[t] : 0;
    s[t] = v;
    __syncthreads();
    for (int off = 1; off < 128; off <<= 1) {
        int a = (t >= off) ? s[t - off] : 0;
        __syncthreads();
        s[t] += a;
        __syncthreads();
    }
    if (t < nblk) partials[t] = s[t] - v;
}

// ---------- scan pass 3: finalize start ----------
__global__ __launch_bounds__(256) void k_scan3(int* __restrict__ start,
                                               const int* __restrict__ partials) {
    int t = threadIdx.x, b = blockIdx.x;
    int add = partials[b];
    int i0 = b * 512 + t, i1 = i0 + 256;
    if (i0 < N_NODES) start[i0] += add;
    if (i1 < N_NODES) start[i1] += add;
    if (b == 0 && t == 0) start[N_NODES] = N_EDGES;
}

// ---------- place records at deterministic positions (plain writes, no atomics) ----------
__global__ __launch_bounds__(256) void k_place(const int* __restrict__ ei,
                                               const float* __restrict__ ew,
                                               const int* __restrict__ start,
                                               const unsigned short* __restrict__ part,
                                               const unsigned short* __restrict__ lrank,
                                               int2* __restrict__ rec) {
    int e = blockIdx.x * blockDim.x + threadIdx.x;
    if (e < N_EDGES) {
        int c = ei[N_EDGES + e];
        int i = e / CHUNK_E;   // compile-time magic-div
        int pos = start[c] + (int)part[(size_t)i * N_NODES + c] + (int)lrank[e];
        rec[pos] = make_int2(ei[e], __float_as_int(ew[e]));
    }
}

// ---------- deg from CSR: dis = rsqrt(1 + sum ew over bucket) ----------
__global__ __launch_bounds__(256) void k_deg(const int* __restrict__ start,
                                             const int2* __restrict__ rec,
                                             float* __restrict__ dis) {
    int n = blockIdx.x * blockDim.x + threadIdx.x;
    if (n < N_NODES) {
        float s = 1.0f;   // self-loop weight
        int j1 = start[n + 1];
        for (int j = start[n]; j < j1; ++j) s += __int_as_float(rec[j].y);
        dis[n] = rsqrtf(s);   // s >= 1 always (self-loop)
    }
}

// ---------- xw = x @ W  (8 rows x 4 cols per thread, float4 LDS reads) ----------
__global__ __launch_bounds__(256) void k_xw(const float* __restrict__ x,
                                            const float* __restrict__ W,
                                            float* __restrict__ xw) {
    __shared__ float Ws[64 * 64];
    __shared__ float xs[128 * 68];
    int t = threadIdx.x;
    int r0 = blockIdx.x * 128;

    for (int i = t; i < 1024; i += 256)
        ((float4*)Ws)[i] = ((const float4*)W)[i];
    for (int i = t; i < 2048; i += 256) {
        int row = i >> 4, k4 = i & 15;
        int gr = r0 + row;
        float4 v = make_float4(0.f, 0.f, 0.f, 0.f);
        if (gr < N_NODES) v = ((const float4*)x)[gr * 16 + k4];
        *(float4*)&xs[row * 68 + k4 * 4] = v;
    }
    __syncthreads();

    int cg = t & 15;
    int rg = t >> 4;
    float4 acc[8];
#pragma unroll
    for (int i = 0; i < 8; ++i) acc[i] = make_float4(0.f, 0.f, 0.f, 0.f);

    for (int k4 = 0; k4 < 16; ++k4) {
        float4 xv[8];
#pragma unroll
        for (int i = 0; i < 8; ++i)
            xv[i] = *(const float4*)&xs[(rg + 16 * i) * 68 + k4 * 4];
        float4 w0 = *(const float4*)&Ws[(k4 * 4 + 0) * 64 + cg * 4];
        float4 w1 = *(const float4*)&Ws[(k4 * 4 + 1) * 64 + cg * 4];
        float4 w2 = *(const float4*)&Ws[(k4 * 4 + 2) * 64 + cg * 4];
        float4 w3 = *(const float4*)&Ws[(k4 * 4 + 3) * 64 + cg * 4];
#pragma unroll
        for (int i = 0; i < 8; ++i) {
            acc[i].x = fmaf(xv[i].x, w0.x, acc[i].x); acc[i].y = fmaf(xv[i].x, w0.y, acc[i].y);
            acc[i].z = fmaf(xv[i].x, w0.z, acc[i].z); acc[i].w = fmaf(xv[i].x, w0.w, acc[i].w);
            acc[i].x = fmaf(xv[i].y, w1.x, acc[i].x); acc[i].y = fmaf(xv[i].y, w1.y, acc[i].y);
            acc[i].z = fmaf(xv[i].y, w1.z, acc[i].z); acc[i].w = fmaf(xv[i].y, w1.w, acc[i].w);
            acc[i].x = fmaf(xv[i].z, w2.x, acc[i].x); acc[i].y = fmaf(xv[i].z, w2.y, acc[i].y);
            acc[i].z = fmaf(xv[i].z, w2.z, acc[i].z); acc[i].w = fmaf(xv[i].z, w2.w, acc[i].w);
            acc[i].x = fmaf(xv[i].w, w3.x, acc[i].x); acc[i].y = fmaf(xv[i].w, w3.y, acc[i].y);
            acc[i].z = fmaf(xv[i].w, w3.z, acc[i].z); acc[i].w = fmaf(xv[i].w, w3.w, acc[i].w);
        }
    }

#pragma unroll
    for (int i = 0; i < 8; ++i) {
        int row = r0 + rg + 16 * i;
        if (row < N_NODES) ((float4*)xw)[row * 16 + cg] = acc[i];
    }
}

// ---------- per-node gather: one wave per node, lane = channel ----------
__global__ __launch_bounds__(256) void k_gather(const int* __restrict__ start,
                                                const int2* __restrict__ rec,
                                                const float* __restrict__ xw,
                                                const float* __restrict__ dis,
                                                const float* __restrict__ bias,
                                                float* __restrict__ out) {
    int wave = threadIdx.x >> 6;
    int c = threadIdx.x & 63;
    int n = blockIdx.x * 4 + wave;   // 12500 * 4 = 50000 exact
    float di = dis[n];
    float acc = di * xw[n * D + c];  // self-loop term (second di applied at the end)
    int j = start[n], jend = start[n + 1];
    int2 r = (j < jend) ? rec[j] : make_int2(0, 0);
    while (j < jend) {
        int2 cur = r;
        if (j + 1 < jend) r = rec[j + 1];
        float w = dis[cur.x] * __int_as_float(cur.y);
        acc = fmaf(xw[cur.x * D + c], w, acc);
        ++j;
    }
    out[n * D + c] = fmaf(acc, di, bias[c]);
}

extern "C" void kernel_launch(void* const* d_in, const int* in_sizes, int n_in,
                              void* d_out, int out_size, void* d_ws, size_t ws_size,
                              hipStream_t stream) {
    const float* x    = (const float*)d_in[0];
    const float* W    = (const float*)d_in[1];
    const float* bias = (const float*)d_in[2];
    const float* ew   = (const float*)d_in[3];
    const int*   ei   = (const int*)d_in[4];   // (2,E) flat: [0:E) src, [E:2E) dst
    float* out = (float*)d_out;

    // ---- workspace layout (4-byte words from base) ----
    // [0, 1.6M)   rec   (int2 x 800000, 6.4 MB)
    // [1.6M,4.8M) xw    (float x 3.2M, 12.8 MB)
    //     aliased before k_xw runs:
    //       lrank: u16 x 800000  (1.6 MB)  -> words [1.6M, 2.0M)
    //       part:  u16 x 64*50000 (6.4 MB) -> words [2.0M, 3.6M)
    // [4.8M...)   dis, cnttot, start(+1), scan partials   (~0.6 MB)
    int2*  rec   = (int2*)d_ws;
    float* xw    = (float*)d_ws + 2 * (size_t)N_EDGES;
    unsigned short* lrank = (unsigned short*)xw;
    unsigned short* part  = (unsigned short*)xw + N_EDGES;
    float* dis      = xw + (size_t)N_NODES * D;
    int*   cnttot   = (int*)(dis + N_NODES);
    int*   start    = cnttot + N_NODES;
    int*   partials = start + N_NODES + 1;

    const int NB_SCAN = (N_NODES + 511) / 512;   // 98
    const int NB_NODE = (N_NODES + 255) / 256;   // 196

    k_hist<<<NCHUNK * NRANGE, 256, 0, stream>>>(ei + N_EDGES, part, lrank);
    k_scanchunks<<<NB_NODE, 256, 0, stream>>>(part, cnttot);
    k_scan1<<<NB_SCAN, 256, 0, stream>>>(cnttot, start, partials);
    k_scan2<<<1, 128, 0, stream>>>(partials, NB_SCAN);
    k_scan3<<<NB_SCAN, 256, 0, stream>>>(start, partials);
    k_place<<<N_EDGES / 256, 256, 0, stream>>>(ei, ew, start, part, lrank, rec);
    k_xw<<<(N_NODES + 127) / 128, 256, 0, stream>>>(x, W, xw);   // clobbers lrank/part (done)
    k_deg<<<NB_NODE, 256, 0, stream>>>(start, rec, dis);
    k_gather<<<N_NODES / 4, 256, 0, stream>>>(start, rec, xw, dis, bias, out);
}

// Round 5
// 112.657 us; speedup vs baseline: 2.2735x; 1.2314x over previous
//
#include <hip/hip_runtime.h>

#define N_NODES 50000
#define N_EDGES 800000
#define D 64
#define NCHUNK 64
#define CHUNK_E (N_EDGES / NCHUNK)   // 12500 edges per chunk
#define NRANGE 8
#define RANGE_N 8192                 // nodes per range (pow2); 8*8192 >= 50000
#define PAD 8                        // bucket padding -> pure unroll-8 gather
#define REC_CAP (N_EDGES + (PAD - 1) * N_NODES)   // 1,150,000 records max

// ---------- LDS histogram + local ranks (no global atomics) ----------
__global__ __launch_bounds__(256) void k_hist(const int* __restrict__ col,
                                              unsigned short* __restrict__ part,
                                              unsigned short* __restrict__ lrank) {
    __shared__ unsigned int h[RANGE_N];   // 32 KiB
    int i = blockIdx.x >> 3;   // chunk 0..63
    int j = blockIdx.x & 7;    // range 0..7
    int t = threadIdx.x;
    for (int k = t; k < RANGE_N; k += 256) h[k] = 0;
    __syncthreads();
    int base = i * CHUNK_E;
    for (int e = base + t; e < base + CHUNK_E; e += 256) {
        int c = col[e];
        if ((c >> 13) == j) {
            unsigned int lr = atomicAdd(&h[c & (RANGE_N - 1)], 1u);
            lrank[e] = (unsigned short)lr;
        }
    }
    __syncthreads();
    for (int k = t; k < RANGE_N; k += 256) {
        int n = j * RANGE_N + k;
        if (n < N_NODES) part[(size_t)i * N_NODES + n] = (unsigned short)h[k];
    }
}

// ---------- per-node exclusive scan over chunk counts; output PADDED total ----------
__global__ __launch_bounds__(256) void k_scanchunks(unsigned short* __restrict__ part,
                                                    int* __restrict__ cnttot) {
    int n = blockIdx.x * blockDim.x + threadIdx.x;
    if (n < N_NODES) {
        unsigned int run = 0;
#pragma unroll 8
        for (int i = 0; i < NCHUNK; ++i) {
            size_t idx = (size_t)i * N_NODES + n;
            unsigned int v = part[idx];
            part[idx] = (unsigned short)run;
            run += v;
        }
        cnttot[n] = (int)((run + PAD - 1) & ~(unsigned)(PAD - 1));
    }
}

// ---------- scan pass 1 over N+1 elements (element N = 0 -> start[N] = total) ----------
__global__ __launch_bounds__(256) void k_scan1(const int* __restrict__ cnt,
                                               int* __restrict__ start,
                                               int* __restrict__ partials) {
    __shared__ int s[512];
    int t = threadIdx.x, b = blockIdx.x;
    int i0 = b * 512 + t, i1 = i0 + 256;
    int v0 = (i0 < N_NODES) ? cnt[i0] : 0;
    int v1 = (i1 < N_NODES) ? cnt[i1] : 0;
    s[t] = v0; s[t + 256] = v1;
    __syncthreads();
    for (int off = 1; off < 512; off <<= 1) {
        int a0 = (t >= off) ? s[t - off] : 0;
        int a1 = s[t + 256 - off];
        __syncthreads();
        s[t] += a0; s[t + 256] += a1;
        __syncthreads();
    }
    if (i0 <= N_NODES) start[i0] = s[t] - v0;
    if (i1 <= N_NODES) start[i1] = s[t + 256] - v1;
    if (t == 255) partials[b] = s[511];
}

// ---------- scan pass 2 ----------
__global__ __launch_bounds__(128) void k_scan2(int* __restrict__ partials, int nblk) {
    __shared__ int s[128];
    int t = threadIdx.x;
    int v = (t < nblk) ? partials[t] : 0;
    s[t] = v;
    __syncthreads();
    for (int off = 1; off < 128; off <<= 1) {
        int a = (t >= off) ? s[t - off] : 0;
        __syncthreads();
        s[t] += a;
        __syncthreads();
    }
    if (t < nblk) partials[t] = s[t] - v;
}

// ---------- scan pass 3 ----------
__global__ __launch_bounds__(256) void k_scan3(int* __restrict__ start,
                                               const int* __restrict__ partials) {
    int t = threadIdx.x, b = blockIdx.x;
    int add = partials[b];
    int i0 = b * 512 + t, i1 = i0 + 256;
    if (i0 <= N_NODES) start[i0] += add;
    if (i1 <= N_NODES) start[i1] += add;
}

// ---------- zero rec (pad slots must be (0, 0.0f)) ----------
__global__ __launch_bounds__(256) void k_zero_rec(float4* __restrict__ rec4) {
    int i = blockIdx.x * blockDim.x + threadIdx.x;
    if (i < (REC_CAP * 8) / 16) rec4[i] = make_float4(0.f, 0.f, 0.f, 0.f);
}

// ---------- place records (src, ew) at deterministic positions ----------
__global__ __launch_bounds__(256) void k_place(const int* __restrict__ ei,
                                               const float* __restrict__ ew,
                                               const int* __restrict__ start,
                                               const unsigned short* __restrict__ part,
                                               const unsigned short* __restrict__ lrank,
                                               int2* __restrict__ rec) {
    int e = blockIdx.x * blockDim.x + threadIdx.x;
    if (e < N_EDGES) {
        int c = ei[N_EDGES + e];
        int i = e / CHUNK_E;
        int pos = start[c] + (int)part[(size_t)i * N_NODES + c] + (int)lrank[e];
        rec[pos] = make_int2(ei[e], __float_as_int(ew[e]));
    }
}

// ---------- deg from CSR: dis = rsqrt(1 + sum ew over bucket); pads add 0 ----------
__global__ __launch_bounds__(256) void k_deg(const int* __restrict__ start,
                                             const int2* __restrict__ rec,
                                             float* __restrict__ dis) {
    int n = blockIdx.x * blockDim.x + threadIdx.x;
    if (n < N_NODES) {
        float s = 1.0f;   // self-loop weight
        int j1 = start[n + 1];
        for (int j = start[n]; j < j1; ++j) s += __int_as_float(rec[j].y);
        dis[n] = rsqrtf(s);
    }
}

// ---------- xw = dis[row] * (x @ W)  (pre-scaled rows) ----------
__global__ __launch_bounds__(256) void k_xw(const float* __restrict__ x,
                                            const float* __restrict__ W,
                                            const float* __restrict__ dis,
                                            float* __restrict__ xw) {
    __shared__ float Ws[64 * 64];
    __shared__ float xs[128 * 68];
    int t = threadIdx.x;
    int r0 = blockIdx.x * 128;

    for (int i = t; i < 1024; i += 256)
        ((float4*)Ws)[i] = ((const float4*)W)[i];
    for (int i = t; i < 2048; i += 256) {
        int row = i >> 4, k4 = i & 15;
        int gr = r0 + row;
        float4 v = make_float4(0.f, 0.f, 0.f, 0.f);
        if (gr < N_NODES) v = ((const float4*)x)[gr * 16 + k4];
        *(float4*)&xs[row * 68 + k4 * 4] = v;
    }
    __syncthreads();

    int cg = t & 15;
    int rg = t >> 4;
    float4 acc[8];
#pragma unroll
    for (int i = 0; i < 8; ++i) acc[i] = make_float4(0.f, 0.f, 0.f, 0.f);

    for (int k4 = 0; k4 < 16; ++k4) {
        float4 xv[8];
#pragma unroll
        for (int i = 0; i < 8; ++i)
            xv[i] = *(const float4*)&xs[(rg + 16 * i) * 68 + k4 * 4];
        float4 w0 = *(const float4*)&Ws[(k4 * 4 + 0) * 64 + cg * 4];
        float4 w1 = *(const float4*)&Ws[(k4 * 4 + 1) * 64 + cg * 4];
        float4 w2 = *(const float4*)&Ws[(k4 * 4 + 2) * 64 + cg * 4];
        float4 w3 = *(const float4*)&Ws[(k4 * 4 + 3) * 64 + cg * 4];
#pragma unroll
        for (int i = 0; i < 8; ++i) {
            acc[i].x = fmaf(xv[i].x, w0.x, acc[i].x); acc[i].y = fmaf(xv[i].x, w0.y, acc[i].y);
            acc[i].z = fmaf(xv[i].x, w0.z, acc[i].z); acc[i].w = fmaf(xv[i].x, w0.w, acc[i].w);
            acc[i].x = fmaf(xv[i].y, w1.x, acc[i].x); acc[i].y = fmaf(xv[i].y, w1.y, acc[i].y);
            acc[i].z = fmaf(xv[i].y, w1.z, acc[i].z); acc[i].w = fmaf(xv[i].y, w1.w, acc[i].w);
            acc[i].x = fmaf(xv[i].z, w2.x, acc[i].x); acc[i].y = fmaf(xv[i].z, w2.y, acc[i].y);
            acc[i].z = fmaf(xv[i].z, w2.z, acc[i].z); acc[i].w = fmaf(xv[i].z, w2.w, acc[i].w);
            acc[i].x = fmaf(xv[i].w, w3.x, acc[i].x); acc[i].y = fmaf(xv[i].w, w3.y, acc[i].y);
            acc[i].z = fmaf(xv[i].w, w3.z, acc[i].z); acc[i].w = fmaf(xv[i].w, w3.w, acc[i].w);
        }
    }

#pragma unroll
    for (int i = 0; i < 8; ++i) {
        int row = r0 + rg + 16 * i;
        if (row < N_NODES) {
            float s = dis[row];
            acc[i].x *= s; acc[i].y *= s; acc[i].z *= s; acc[i].w *= s;
            ((float4*)xw)[row * 16 + cg] = acc[i];
        }
    }
}

// ---------- per-node gather: one wave per node, pure unroll-8, 8 loads in flight ----------
__global__ __launch_bounds__(256) void k_gather(const int* __restrict__ start,
                                                const int2* __restrict__ rec,
                                                const float* __restrict__ xw,
                                                const float* __restrict__ dis,
                                                const float* __restrict__ bias,
                                                float* __restrict__ out) {
    int wave = threadIdx.x >> 6;
    int c = threadIdx.x & 63;
    int n = blockIdx.x * 4 + wave;   // 12500 * 4 = 50000 exact
    float di = dis[n];
    float acc0 = xw[n * D + c];      // self-loop term (xw pre-scaled by dis)
    float acc1 = 0.f, acc2 = 0.f, acc3 = 0.f, acc4 = 0.f, acc5 = 0.f, acc6 = 0.f, acc7 = 0.f;
    int j = start[n], jend = start[n + 1];   // multiple of 8 edges (zero-padded)
    for (; j < jend; j += 8) {
        int2 r0 = rec[j + 0], r1 = rec[j + 1], r2 = rec[j + 2], r3 = rec[j + 3];
        int2 r4 = rec[j + 4], r5 = rec[j + 5], r6 = rec[j + 6], r7 = rec[j + 7];
        float v0 = xw[r0.x * D + c], v1 = xw[r1.x * D + c];
        float v2 = xw[r2.x * D + c], v3 = xw[r3.x * D + c];
        float v4 = xw[r4.x * D + c], v5 = xw[r5.x * D + c];
        float v6 = xw[r6.x * D + c], v7 = xw[r7.x * D + c];
        acc0 = fmaf(v0, __int_as_float(r0.y), acc0);
        acc1 = fmaf(v1, __int_as_float(r1.y), acc1);
        acc2 = fmaf(v2, __int_as_float(r2.y), acc2);
        acc3 = fmaf(v3, __int_as_float(r3.y), acc3);
        acc4 = fmaf(v4, __int_as_float(r4.y), acc4);
        acc5 = fmaf(v5, __int_as_float(r5.y), acc5);
        acc6 = fmaf(v6, __int_as_float(r6.y), acc6);
        acc7 = fmaf(v7, __int_as_float(r7.y), acc7);
    }
    float acc = ((acc0 + acc1) + (acc2 + acc3)) + ((acc4 + acc5) + (acc6 + acc7));
    out[n * D + c] = fmaf(acc, di, bias[c]);
}

extern "C" void kernel_launch(void* const* d_in, const int* in_sizes, int n_in,
                              void* d_out, int out_size, void* d_ws, size_t ws_size,
                              hipStream_t stream) {
    const float* x    = (const float*)d_in[0];
    const float* W    = (const float*)d_in[1];
    const float* bias = (const float*)d_in[2];
    const float* ew   = (const float*)d_in[3];
    const int*   ei   = (const int*)d_in[4];   // (2,E) flat: [0:E) src, [E:2E) dst
    float* out = (float*)d_out;

    // ---- workspace layout (4-byte words) ----
    // rec:   int2 x REC_CAP            (9.2 MB)
    // xw:    float x N*D               (12.8 MB)  -- aliased by lrank/part until k_xw
    // dis, cnttot, start(+1), partials (~0.6 MB)
    int2*  rec   = (int2*)d_ws;
    float* xw    = (float*)d_ws + 2 * (size_t)REC_CAP;
    unsigned short* lrank = (unsigned short*)xw;                 // 1.6 MB
    unsigned short* part  = (unsigned short*)xw + N_EDGES;       // 6.4 MB
    float* dis      = xw + (size_t)N_NODES * D;
    int*   cnttot   = (int*)(dis + N_NODES);
    int*   start    = cnttot + N_NODES;
    int*   partials = start + N_NODES + 1;

    const int NB_SCAN = (N_NODES + 1 + 511) / 512;   // 98 (covers N+1 elements)
    const int NB_NODE = (N_NODES + 255) / 256;       // 196

    k_hist<<<NCHUNK * NRANGE, 256, 0, stream>>>(ei + N_EDGES, part, lrank);
    k_scanchunks<<<NB_NODE, 256, 0, stream>>>(part, cnttot);
    k_scan1<<<NB_SCAN, 256, 0, stream>>>(cnttot, start, partials);
    k_scan2<<<1, 128, 0, stream>>>(partials, NB_SCAN);
    k_scan3<<<NB_SCAN, 256, 0, stream>>>(start, partials);
    k_zero_rec<<<((REC_CAP * 8 / 16) + 255) / 256, 256, 0, stream>>>((float4*)rec);
    k_place<<<N_EDGES / 256, 256, 0, stream>>>(ei, ew, start, part, lrank, rec);
    k_deg<<<NB_NODE, 256, 0, stream>>>(start, rec, dis);
    k_xw<<<(N_NODES + 127) / 128, 256, 0, stream>>>(x, W, dis, xw);  // clobbers lrank/part (done)
    k_gather<<<N_NODES / 4, 256, 0, stream>>>(start, rec, xw, dis, bias, out);
}